// Round 17
// baseline (62.474 us; speedup 1.0000x reference)
//
#include <hip/hip_runtime.h>

// EKF_v2: B=16384, N=128, DX=5, DZ=2.
// DETERMINISM-FIRST redesign. Evidence: VALU-only rounds passed 8/8; MFMA
// rounds passed 3/8 with an identical-source pass/fail pair (R13 pass,
// R16 fail) proving environment/HW-sensitive corruption on the MFMA path.
// This kernel: R13 skeleton (wave=batch, 2 particles/lane, direct I/O,
// single-phase 14-chain butterfly) + layer-2/3 on VALU with 4 independent
// FMA chains (R8's ILP form), weights staged once into a 2.5KB LDS table
// (uniform broadcast ds_read_b128). Self-contained; no d_ws; no MFMA.

#define NBPB 4  // batches (=waves) per block

__global__ __launch_bounds__(256) void ekf_fused(
    const float* __restrict__ state_old,  // (B,128,5)
    const float* __restrict__ y_obs,      // (B,128,2)
    const float* __restrict__ encoding,   // (B,128)
    const float* __restrict__ pw1,        // (2,16)
    const float* __restrict__ pb1,        // (16)
    const float* __restrict__ pw2,        // (16,32)
    const float* __restrict__ pb2,        // (32)
    const float* __restrict__ pw3,        // (32,2)
    const float* __restrict__ pb3,        // (2)
    const float* __restrict__ nw1,        // (128,32)
    const float* __restrict__ nb1,        // (32)
    const float* __restrict__ nw2,        // (32,2)
    const float* __restrict__ nb2,        // (2)
    const float* __restrict__ lob,        // (2)
    const float* __restrict__ fob,        // (2)
    float* __restrict__ out)              // (B,128,5)
{
    __shared__ __align__(16) float s_state[NBPB * 640];
    // s_wt[j*20 + r]: r<16 -> pw2[r][j] (pw2^T), 16 -> pb2[j],
    //                 17 -> pw3[j][0], 18 -> pw3[j][1], 19 -> pad.
    // j*20 floats = 80 B, 16B-aligned -> float4 reads at +0,+4,+8,+12 legal.
    __shared__ __align__(16) float s_wt[32 * 20];

    const int t = threadIdx.x;
    const int base = blockIdx.x * NBPB;

    // ---- stage state (coalesced float4) + weight table ----
    {
        const float4* src = (const float4*)(state_old + (size_t)base * 640);
        float4* dst = (float4*)s_state;
        #pragma unroll
        for (int i = t; i < NBPB * 160; i += 256) dst[i] = src[i];
        for (int idx = t; idx < 640; idx += 256) {
            int j = idx / 20, r = idx % 20;
            float v;
            if (r < 16)       v = pw2[r * 32 + j];
            else if (r == 16) v = pb2[j];
            else if (r == 17) v = pw3[2 * j];
            else if (r == 18) v = pw3[2 * j + 1];
            else              v = 0.0f;
            s_wt[idx] = v;
        }
    }
    __syncthreads();

    const int w = t >> 6;    // wave = batch within block
    const int l = t & 63;
    const int c = l & 31;    // particle column
    const int h = l >> 5;    // lane half -> k-split & particle ownership
    const size_t b = (size_t)base + w;

    // ---- noise MLP: j = c, k-range split across halves (R13-proven) ----
    float diag0, diag1;
    {
        const float4* eg4 = (const float4*)(encoding + b * 128) + h * 16;
        const float* wp = nw1 + (size_t)(h * 64) * 32 + c;
        float a0 = 0.f, a1 = 0.f, a2 = 0.f, a3 = 0.f;
        #pragma unroll
        for (int kk = 0; kk < 16; ++kk) {
            float4 e4 = eg4[kk];
            a0 = fmaf(e4.x, wp[(4 * kk + 0) * 32], a0);
            a1 = fmaf(e4.y, wp[(4 * kk + 1) * 32], a1);
            a2 = fmaf(e4.z, wp[(4 * kk + 2) * 32], a2);
            a3 = fmaf(e4.w, wp[(4 * kk + 3) * 32], a3);
        }
        float acc = (a0 + a1) + (a2 + a3);
        acc += __shfl_xor(acc, 32, 64);   // combine k-halves
        acc += nb1[c];
        float hh = fmaxf(acc, 0.f);
        float d0 = hh * nw2[2 * c + 0];
        float d1 = hh * nw2[2 * c + 1];
        #pragma unroll
        for (int off = 1; off < 32; off <<= 1) {
            d0 += __shfl_xor(d0, off, 64);
            d1 += __shfl_xor(d1, off, 64);
        }
        float e0 = d0 + nb2[0] + lob[0];
        float e1 = d1 + nb2[1] + lob[1];
        diag0 = fmaf(e0, e0, fob[0]);
        diag1 = fmaf(e1, e1, fob[1]);
    }

    const float* sp = s_state + w * 640;
    const int p0 = c + 32 * (2 * h);
    const int p1 = c + 32 * (2 * h + 1);

    // ---- process model pose + layer-1 for the 2 owned particles ----
    float xpo[2][5];
    float va, tda, vb, tdb;
    {
        const float* s5a = sp + p0 * 5;
        const float* s5b = sp + p1 * 5;
        va = s5a[3]; tda = s5a[4];
        vb = s5b[3]; tdb = s5b[4];
        float tha = s5a[2] + tda;
        float thb = s5b[2] + tdb;
        xpo[0][0] = fmaf(va, __sinf(tha), s5a[0]);
        xpo[0][1] = fmaf(va, __cosf(tha), s5a[1]);
        xpo[0][2] = tha;
        xpo[1][0] = fmaf(vb, __sinf(thb), s5b[0]);
        xpo[1][1] = fmaf(vb, __cosf(thb), s5b[1]);
        xpo[1][2] = thb;
    }
    float h1a[16], h1b[16];
    #pragma unroll
    for (int q = 0; q < 16; ++q) {
        float w0 = pw1[q], w1 = pw1[16 + q], bq = pb1[q]; // uniform -> s_load
        h1a[q] = fmaxf(0.f, fmaf(va, w0, fmaf(tda, w1, bq)));
        h1b[q] = fmaxf(0.f, fmaf(vb, w0, fmaf(tdb, w1, bq)));
    }

    // ---- layers 2+3 on VALU: 2 particles x unroll-2 = 4 indep chains ----
    float o3a = 0.f, o4a = 0.f, o3b = 0.f, o4b = 0.f;
    #pragma unroll 2
    for (int j = 0; j < 32; ++j) {
        const float* wj = s_wt + j * 20;      // uniform broadcast reads
        float4 w0 = *(const float4*)(wj);
        float4 w1 = *(const float4*)(wj + 4);
        float4 w2 = *(const float4*)(wj + 8);
        float4 w3 = *(const float4*)(wj + 12);
        float pb2j = wj[16];
        float acca = pb2j, accb = pb2j;
        acca = fmaf(h1a[0],  w0.x, acca); accb = fmaf(h1b[0],  w0.x, accb);
        acca = fmaf(h1a[1],  w0.y, acca); accb = fmaf(h1b[1],  w0.y, accb);
        acca = fmaf(h1a[2],  w0.z, acca); accb = fmaf(h1b[2],  w0.z, accb);
        acca = fmaf(h1a[3],  w0.w, acca); accb = fmaf(h1b[3],  w0.w, accb);
        acca = fmaf(h1a[4],  w1.x, acca); accb = fmaf(h1b[4],  w1.x, accb);
        acca = fmaf(h1a[5],  w1.y, acca); accb = fmaf(h1b[5],  w1.y, accb);
        acca = fmaf(h1a[6],  w1.z, acca); accb = fmaf(h1b[6],  w1.z, accb);
        acca = fmaf(h1a[7],  w1.w, acca); accb = fmaf(h1b[7],  w1.w, accb);
        acca = fmaf(h1a[8],  w2.x, acca); accb = fmaf(h1b[8],  w2.x, accb);
        acca = fmaf(h1a[9],  w2.y, acca); accb = fmaf(h1b[9],  w2.y, accb);
        acca = fmaf(h1a[10], w2.z, acca); accb = fmaf(h1b[10], w2.z, accb);
        acca = fmaf(h1a[11], w2.w, acca); accb = fmaf(h1b[11], w2.w, accb);
        acca = fmaf(h1a[12], w3.x, acca); accb = fmaf(h1b[12], w3.x, accb);
        acca = fmaf(h1a[13], w3.y, acca); accb = fmaf(h1b[13], w3.y, accb);
        acca = fmaf(h1a[14], w3.z, acca); accb = fmaf(h1b[14], w3.z, accb);
        acca = fmaf(h1a[15], w3.w, acca); accb = fmaf(h1b[15], w3.w, accb);
        float ra = fmaxf(acca, 0.f), rb = fmaxf(accb, 0.f);
        float w30 = wj[17], w31 = wj[18];
        o3a = fmaf(ra, w30, o3a); o4a = fmaf(ra, w31, o4a);
        o3b = fmaf(rb, w30, o3b); o4b = fmaf(rb, w31, o4b);
    }
    {
        float pb30 = pb3[0], pb31 = pb3[1];
        xpo[0][3] = va + o3a + pb30;
        xpo[0][4] = tda + o4a + pb31;
        xpo[1][3] = vb + o3b + pb30;
        xpo[1][4] = tdb + o4b + pb31;
    }

    // ---- raw moments: ONE butterfly phase (6 levels), 14 chains ----
    float red[14];
    #pragma unroll
    for (int i = 0; i < 5; ++i) red[i] = xpo[0][i] + xpo[1][i];
    red[5]  = xpo[0][0] * xpo[0][3] + xpo[1][0] * xpo[1][3];
    red[6]  = xpo[0][0] * xpo[0][4] + xpo[1][0] * xpo[1][4];
    red[7]  = xpo[0][1] * xpo[0][3] + xpo[1][1] * xpo[1][3];
    red[8]  = xpo[0][1] * xpo[0][4] + xpo[1][1] * xpo[1][4];
    red[9]  = xpo[0][2] * xpo[0][3] + xpo[1][2] * xpo[1][3];
    red[10] = xpo[0][2] * xpo[0][4] + xpo[1][2] * xpo[1][4];
    red[11] = xpo[0][3] * xpo[0][3] + xpo[1][3] * xpo[1][3];
    red[12] = xpo[0][3] * xpo[0][4] + xpo[1][3] * xpo[1][4];
    red[13] = xpo[0][4] * xpo[0][4] + xpo[1][4] * xpo[1][4];
    #pragma unroll
    for (int off = 1; off < 64; off <<= 1) {
        #pragma unroll
        for (int r = 0; r < 14; ++r)
            red[r] += __shfl_xor(red[r], off, 64);
    }

    // ---- covariances + analytic 2x2 solve ----
    const float inv  = 1.0f / 127.0f;
    const float minv = inv * 0.0078125f; // 1/(127*128)
    float S00 = red[5]  * inv - red[0] * red[3] * minv;
    float S01 = red[6]  * inv - red[0] * red[4] * minv;
    float S10 = red[7]  * inv - red[1] * red[3] * minv;
    float S11 = red[8]  * inv - red[1] * red[4] * minv;
    float S20 = red[9]  * inv - red[2] * red[3] * minv;
    float S21 = red[10] * inv - red[2] * red[4] * minv;
    float S30 = red[11] * inv - red[3] * red[3] * minv;
    float S31 = red[12] * inv - red[3] * red[4] * minv;
    float S40 = S31;
    float S41 = red[13] * inv - red[4] * red[4] * minv;
    float p00 = S30 + diag0, p01 = S31, p10 = S40, p11 = S41 + diag1;
    float rdet = 1.0f / (p00 * p11 - p01 * p10);
    float Ka0 = (p11 * S00 - p01 * S01) * rdet, Kb0 = (p00 * S01 - p10 * S00) * rdet;
    float Ka1 = (p11 * S10 - p01 * S11) * rdet, Kb1 = (p00 * S11 - p10 * S10) * rdet;
    float Ka2 = (p11 * S20 - p01 * S21) * rdet, Kb2 = (p00 * S21 - p10 * S20) * rdet;
    float Ka3 = (p11 * S30 - p01 * S31) * rdet, Kb3 = (p00 * S31 - p10 * S30) * rdet;
    float Ka4 = (p11 * S40 - p01 * S41) * rdet, Kb4 = (p00 * S41 - p10 * S40) * rdet;

    // ---- Kalman update + direct stores (2 owned particles) ----
    #pragma unroll
    for (int mm = 0; mm < 2; ++mm) {
        const int p = c + 32 * (2 * h + mm);
        const float2 yy = *(const float2*)(y_obs + (b * 128 + (size_t)p) * 2);
        float i0 = yy.x - xpo[mm][3];
        float i1 = yy.y - xpo[mm][4];
        float* o = out + (b * 128 + (size_t)p) * 5;
        o[0] = xpo[mm][0] + i0 * Ka0 + i1 * Kb0;
        o[1] = xpo[mm][1] + i0 * Ka1 + i1 * Kb1;
        o[2] = xpo[mm][2] + i0 * Ka2 + i1 * Kb2;
        o[3] = xpo[mm][3] + i0 * Ka3 + i1 * Kb3;
        o[4] = xpo[mm][4] + i0 * Ka4 + i1 * Kb4;
    }
}

extern "C" void kernel_launch(void* const* d_in, const int* in_sizes, int n_in,
                              void* d_out, int out_size, void* d_ws, size_t ws_size,
                              hipStream_t stream) {
    const float* state_old = (const float*)d_in[0];
    const float* y_obs     = (const float*)d_in[1];
    const float* encoding  = (const float*)d_in[2];
    const float* pw1 = (const float*)d_in[3];
    const float* pb1 = (const float*)d_in[4];
    const float* pw2 = (const float*)d_in[5];
    const float* pb2 = (const float*)d_in[6];
    const float* pw3 = (const float*)d_in[7];
    const float* pb3 = (const float*)d_in[8];
    const float* nw1 = (const float*)d_in[9];
    const float* nb1 = (const float*)d_in[10];
    const float* nw2 = (const float*)d_in[11];
    const float* nb2 = (const float*)d_in[12];
    const float* lob = (const float*)d_in[13];
    const float* fob = (const float*)d_in[14];
    float* out = (float*)d_out;

    const int B = 16384;
    dim3 grid(B / NBPB);
    dim3 block(256);
    hipLaunchKernelGGL(ekf_fused, grid, block, 0, stream,
                       state_old, y_obs, encoding,
                       pw1, pb1, pw2, pb2, pw3, pb3,
                       nw1, nb1, nw2, nb2, lob, fob, out);
}

// Round 18
// 61.105 us; speedup vs baseline: 1.0224x; 1.0224x over previous
//
#include <hip/hip_runtime.h>

// EKF_v2: B=16384, N=128, DX=5, DZ=2.
// R17 (VALU-only, PASSED 62.5us, VGPR 52, VALUBusy ~60%) + ONE change:
// layer-1 and layer-2/3 computed on particle PAIRS via v_pk_fma_f32
// (VOP3P packed fp32, 2 IEEE-exact FMAs/issue; weight splat in both
// halves). Halves the dominant ~1150-instr loop. Bit-identical rounding
// to fmaf -> absmax unchanged. Still no MFMA, no d_ws (9/9 determinism
// record for VALU kernels). Gates: VGPR<=64, dur < 62.5 else revert.

#define NBPB 4  // batches (=waves) per block

typedef float v2f __attribute__((ext_vector_type(2)));
__device__ __forceinline__ v2f spl(float x) { v2f r; r.x = x; r.y = x; return r; }

__global__ __launch_bounds__(256) void ekf_fused(
    const float* __restrict__ state_old,  // (B,128,5)
    const float* __restrict__ y_obs,      // (B,128,2)
    const float* __restrict__ encoding,   // (B,128)
    const float* __restrict__ pw1,        // (2,16)
    const float* __restrict__ pb1,        // (16)
    const float* __restrict__ pw2,        // (16,32)
    const float* __restrict__ pb2,        // (32)
    const float* __restrict__ pw3,        // (32,2)
    const float* __restrict__ pb3,        // (2)
    const float* __restrict__ nw1,        // (128,32)
    const float* __restrict__ nb1,        // (32)
    const float* __restrict__ nw2,        // (32,2)
    const float* __restrict__ nb2,        // (2)
    const float* __restrict__ lob,        // (2)
    const float* __restrict__ fob,        // (2)
    float* __restrict__ out)              // (B,128,5)
{
    __shared__ __align__(16) float s_state[NBPB * 640];
    // s_wt[j*20 + r]: r<16 -> pw2[r][j] (pw2^T), 16 -> pb2[j],
    //                 17 -> pw3[j][0], 18 -> pw3[j][1], 19 -> pad.
    __shared__ __align__(16) float s_wt[32 * 20];

    const int t = threadIdx.x;
    const int base = blockIdx.x * NBPB;

    // ---- stage state (coalesced float4) + weight table ----
    {
        const float4* src = (const float4*)(state_old + (size_t)base * 640);
        float4* dst = (float4*)s_state;
        #pragma unroll
        for (int i = t; i < NBPB * 160; i += 256) dst[i] = src[i];
        for (int idx = t; idx < 640; idx += 256) {
            int j = idx / 20, r = idx % 20;
            float v;
            if (r < 16)       v = pw2[r * 32 + j];
            else if (r == 16) v = pb2[j];
            else if (r == 17) v = pw3[2 * j];
            else if (r == 18) v = pw3[2 * j + 1];
            else              v = 0.0f;
            s_wt[idx] = v;
        }
    }
    __syncthreads();

    const int w = t >> 6;    // wave = batch within block
    const int l = t & 63;
    const int c = l & 31;    // particle column
    const int h = l >> 5;    // lane half -> k-split & particle ownership
    const size_t b = (size_t)base + w;

    // ---- noise MLP: j = c, k-range split across halves ----
    float diag0, diag1;
    {
        const float4* eg4 = (const float4*)(encoding + b * 128) + h * 16;
        const float* wp = nw1 + (size_t)(h * 64) * 32 + c;
        float a0 = 0.f, a1 = 0.f, a2 = 0.f, a3 = 0.f;
        #pragma unroll
        for (int kk = 0; kk < 16; ++kk) {
            float4 e4 = eg4[kk];
            a0 = fmaf(e4.x, wp[(4 * kk + 0) * 32], a0);
            a1 = fmaf(e4.y, wp[(4 * kk + 1) * 32], a1);
            a2 = fmaf(e4.z, wp[(4 * kk + 2) * 32], a2);
            a3 = fmaf(e4.w, wp[(4 * kk + 3) * 32], a3);
        }
        float acc = (a0 + a1) + (a2 + a3);
        acc += __shfl_xor(acc, 32, 64);   // combine k-halves
        acc += nb1[c];
        float hh = fmaxf(acc, 0.f);
        float d0 = hh * nw2[2 * c + 0];
        float d1 = hh * nw2[2 * c + 1];
        #pragma unroll
        for (int off = 1; off < 32; off <<= 1) {
            d0 += __shfl_xor(d0, off, 64);
            d1 += __shfl_xor(d1, off, 64);
        }
        float e0 = d0 + nb2[0] + lob[0];
        float e1 = d1 + nb2[1] + lob[1];
        diag0 = fmaf(e0, e0, fob[0]);
        diag1 = fmaf(e1, e1, fob[1]);
    }

    const float* sp = s_state + w * 640;
    const int p0 = c + 32 * (2 * h);
    const int p1 = c + 32 * (2 * h + 1);

    // ---- process model pose for the 2 owned particles ----
    float xpo[2][5];
    float va, tda, vb, tdb;
    {
        const float* s5a = sp + p0 * 5;
        const float* s5b = sp + p1 * 5;
        va = s5a[3]; tda = s5a[4];
        vb = s5b[3]; tdb = s5b[4];
        float tha = s5a[2] + tda;
        float thb = s5b[2] + tdb;
        xpo[0][0] = fmaf(va, __sinf(tha), s5a[0]);
        xpo[0][1] = fmaf(va, __cosf(tha), s5a[1]);
        xpo[0][2] = tha;
        xpo[1][0] = fmaf(vb, __sinf(thb), s5b[0]);
        xpo[1][1] = fmaf(vb, __cosf(thb), s5b[1]);
        xpo[1][2] = thb;
    }

    // ---- layer-1 packed: h1p[q] = (h1a[q], h1b[q]) via v_pk_fma_f32 ----
    v2f h1p[16];
    {
        v2f vv;  vv.x = va;  vv.y = vb;
        v2f tdv; tdv.x = tda; tdv.y = tdb;
        #pragma unroll
        for (int q = 0; q < 16; ++q) {
            v2f tmp = __builtin_elementwise_fma(tdv, spl(pw1[16 + q]), spl(pb1[q]));
            v2f hq  = __builtin_elementwise_fma(vv, spl(pw1[q]), tmp);
            h1p[q] = __builtin_elementwise_max(hq, spl(0.0f));
        }
    }

    // ---- layers 2+3 packed: per j one packed acc chain; unroll 2 for ILP ----
    v2f o3p = spl(0.0f), o4p = spl(0.0f);
    #pragma unroll 2
    for (int j = 0; j < 32; ++j) {
        const float* wj = s_wt + j * 20;      // uniform broadcast reads
        float4 w0 = *(const float4*)(wj);
        float4 w1 = *(const float4*)(wj + 4);
        float4 w2 = *(const float4*)(wj + 8);
        float4 w3 = *(const float4*)(wj + 12);
        v2f acc = spl(wj[16]);
        acc = __builtin_elementwise_fma(h1p[0],  spl(w0.x), acc);
        acc = __builtin_elementwise_fma(h1p[1],  spl(w0.y), acc);
        acc = __builtin_elementwise_fma(h1p[2],  spl(w0.z), acc);
        acc = __builtin_elementwise_fma(h1p[3],  spl(w0.w), acc);
        acc = __builtin_elementwise_fma(h1p[4],  spl(w1.x), acc);
        acc = __builtin_elementwise_fma(h1p[5],  spl(w1.y), acc);
        acc = __builtin_elementwise_fma(h1p[6],  spl(w1.z), acc);
        acc = __builtin_elementwise_fma(h1p[7],  spl(w1.w), acc);
        acc = __builtin_elementwise_fma(h1p[8],  spl(w2.x), acc);
        acc = __builtin_elementwise_fma(h1p[9],  spl(w2.y), acc);
        acc = __builtin_elementwise_fma(h1p[10], spl(w2.z), acc);
        acc = __builtin_elementwise_fma(h1p[11], spl(w2.w), acc);
        acc = __builtin_elementwise_fma(h1p[12], spl(w3.x), acc);
        acc = __builtin_elementwise_fma(h1p[13], spl(w3.y), acc);
        acc = __builtin_elementwise_fma(h1p[14], spl(w3.z), acc);
        acc = __builtin_elementwise_fma(h1p[15], spl(w3.w), acc);
        v2f r = __builtin_elementwise_max(acc, spl(0.0f));
        o3p = __builtin_elementwise_fma(r, spl(wj[17]), o3p);
        o4p = __builtin_elementwise_fma(r, spl(wj[18]), o4p);
    }
    {
        float pb30 = pb3[0], pb31 = pb3[1];
        xpo[0][3] = va + o3p.x + pb30;
        xpo[0][4] = tda + o4p.x + pb31;
        xpo[1][3] = vb + o3p.y + pb30;
        xpo[1][4] = tdb + o4p.y + pb31;
    }

    // ---- raw moments: ONE butterfly phase (6 levels), 14 chains ----
    float red[14];
    #pragma unroll
    for (int i = 0; i < 5; ++i) red[i] = xpo[0][i] + xpo[1][i];
    red[5]  = xpo[0][0] * xpo[0][3] + xpo[1][0] * xpo[1][3];
    red[6]  = xpo[0][0] * xpo[0][4] + xpo[1][0] * xpo[1][4];
    red[7]  = xpo[0][1] * xpo[0][3] + xpo[1][1] * xpo[1][3];
    red[8]  = xpo[0][1] * xpo[0][4] + xpo[1][1] * xpo[1][4];
    red[9]  = xpo[0][2] * xpo[0][3] + xpo[1][2] * xpo[1][3];
    red[10] = xpo[0][2] * xpo[0][4] + xpo[1][2] * xpo[1][4];
    red[11] = xpo[0][3] * xpo[0][3] + xpo[1][3] * xpo[1][3];
    red[12] = xpo[0][3] * xpo[0][4] + xpo[1][3] * xpo[1][4];
    red[13] = xpo[0][4] * xpo[0][4] + xpo[1][4] * xpo[1][4];
    #pragma unroll
    for (int off = 1; off < 64; off <<= 1) {
        #pragma unroll
        for (int r = 0; r < 14; ++r)
            red[r] += __shfl_xor(red[r], off, 64);
    }

    // ---- covariances + analytic 2x2 solve ----
    const float inv  = 1.0f / 127.0f;
    const float minv = inv * 0.0078125f; // 1/(127*128)
    float S00 = red[5]  * inv - red[0] * red[3] * minv;
    float S01 = red[6]  * inv - red[0] * red[4] * minv;
    float S10 = red[7]  * inv - red[1] * red[3] * minv;
    float S11 = red[8]  * inv - red[1] * red[4] * minv;
    float S20 = red[9]  * inv - red[2] * red[3] * minv;
    float S21 = red[10] * inv - red[2] * red[4] * minv;
    float S30 = red[11] * inv - red[3] * red[3] * minv;
    float S31 = red[12] * inv - red[3] * red[4] * minv;
    float S40 = S31;
    float S41 = red[13] * inv - red[4] * red[4] * minv;
    float p00 = S30 + diag0, p01 = S31, p10 = S40, p11 = S41 + diag1;
    float rdet = 1.0f / (p00 * p11 - p01 * p10);
    float Ka0 = (p11 * S00 - p01 * S01) * rdet, Kb0 = (p00 * S01 - p10 * S00) * rdet;
    float Ka1 = (p11 * S10 - p01 * S11) * rdet, Kb1 = (p00 * S11 - p10 * S10) * rdet;
    float Ka2 = (p11 * S20 - p01 * S21) * rdet, Kb2 = (p00 * S21 - p10 * S20) * rdet;
    float Ka3 = (p11 * S30 - p01 * S31) * rdet, Kb3 = (p00 * S31 - p10 * S30) * rdet;
    float Ka4 = (p11 * S40 - p01 * S41) * rdet, Kb4 = (p00 * S41 - p10 * S40) * rdet;

    // ---- Kalman update + direct stores (2 owned particles) ----
    #pragma unroll
    for (int mm = 0; mm < 2; ++mm) {
        const int p = c + 32 * (2 * h + mm);
        const float2 yy = *(const float2*)(y_obs + (b * 128 + (size_t)p) * 2);
        float i0 = yy.x - xpo[mm][3];
        float i1 = yy.y - xpo[mm][4];
        float* o = out + (b * 128 + (size_t)p) * 5;
        o[0] = xpo[mm][0] + i0 * Ka0 + i1 * Kb0;
        o[1] = xpo[mm][1] + i0 * Ka1 + i1 * Kb1;
        o[2] = xpo[mm][2] + i0 * Ka2 + i1 * Kb2;
        o[3] = xpo[mm][3] + i0 * Ka3 + i1 * Kb3;
        o[4] = xpo[mm][4] + i0 * Ka4 + i1 * Kb4;
    }
}

extern "C" void kernel_launch(void* const* d_in, const int* in_sizes, int n_in,
                              void* d_out, int out_size, void* d_ws, size_t ws_size,
                              hipStream_t stream) {
    const float* state_old = (const float*)d_in[0];
    const float* y_obs     = (const float*)d_in[1];
    const float* encoding  = (const float*)d_in[2];
    const float* pw1 = (const float*)d_in[3];
    const float* pb1 = (const float*)d_in[4];
    const float* pw2 = (const float*)d_in[5];
    const float* pb2 = (const float*)d_in[6];
    const float* pw3 = (const float*)d_in[7];
    const float* pb3 = (const float*)d_in[8];
    const float* nw1 = (const float*)d_in[9];
    const float* nb1 = (const float*)d_in[10];
    const float* nw2 = (const float*)d_in[11];
    const float* nb2 = (const float*)d_in[12];
    const float* lob = (const float*)d_in[13];
    const float* fob = (const float*)d_in[14];
    float* out = (float*)d_out;

    const int B = 16384;
    dim3 grid(B / NBPB);
    dim3 block(256);
    hipLaunchKernelGGL(ekf_fused, grid, block, 0, stream,
                       state_old, y_obs, encoding,
                       pw1, pb1, pw2, pb2, pw3, pb3,
                       nw1, nb1, nw2, nb2, lob, fob, out);
}